// Round 11
// baseline (154.894 us; speedup 1.0000x reference)
//
#include <hip/hip_runtime.h>

typedef _Float16 half_t;
typedef _Float16 h2 __attribute__((ext_vector_type(2)));
typedef _Float16 h4 __attribute__((ext_vector_type(4)));

__device__ __forceinline__ float fdot2f(h2 a, h2 b, float c) {
#if __has_builtin(__builtin_amdgcn_fdot2)
    return __builtin_amdgcn_fdot2(a, b, c, false);
#else
    return c + (float)a.x * (float)b.x + (float)a.y * (float)b.y;
#endif
}

// ---- prep: weights -> ws once. ws layout: wdt fp32 [0,320) ; w2h half ; w3h after.
__global__ __launch_bounds__(256) void prep_kernel(
    const float* __restrict__ w2g, const float* __restrict__ w3g,
    const float* __restrict__ wdg, float* __restrict__ wsW)
{
    const int tid = threadIdx.x;
    half_t* w2h = (half_t*)(wsW + 320);
    half_t* w3h = w2h + 1152;
    for (int i = tid; i < 320; i += 256) {             // wdt[c2*10+j] = wd[j][c2]
        int j = i >> 5, c2 = i & 31;
        wsW[c2 * 10 + j] = wdg[i];
    }
    for (int i = tid; i < 1152; i += 256) {            // w2h[((k*2+g)*16+c)*4+l] = w2[c][g*4+l][k]
        int l = i & 3, c = (i >> 2) & 15, g = (i >> 6) & 1, k = i >> 7;
        w2h[i] = (half_t)w2g[(c * 8 + g * 4 + l) * 9 + k];
    }
    for (int i = tid; i < 4608; i += 256) {            // w3h[((k*4+g)*32+c)*4+l] = w3[c][g*4+l][k]
        int l = i & 3, c = (i >> 2) & 31, g = (i >> 7) & 3, k = i >> 9;
        w3h[i] = (half_t)w3g[(c * 16 + g * 4 + l) * 9 + k];
    }
}

// 4 images per block, 512 threads (grid 2048); 128 threads (2 waves) per image.
// Per-thread dependency chains halved vs R10: stage2 oc-pairs, stage3 g-halves.
__global__ __launch_bounds__(512, 6) void cnn_kernel(
    const float* __restrict__ seq,
    const float* __restrict__ w1g, const float* __restrict__ b1g,
    const float* __restrict__ b2g, const float* __restrict__ b3g,
    const float* __restrict__ bdg, const float* __restrict__ wsW,
    float* __restrict__ out)
{
    __shared__ __align__(16) float  s_img2[4][28][28];      // parity: [0..13]=even, [14..27]=odd
    __shared__ __align__(16) half_t s_p1n[4][2][10][11][4]; // [img][g][y][slot][l]; ic=g*4+l
    __shared__ __align__(16) half_t s_p2n[4][16][16];       // [img][pixel(y*4+x)][16 ic]
    __shared__ float s_p3[4][32];

    const int tid   = threadIdx.x;
    const int mbase = blockIdx.x * 4;
    const float*  wdt = wsW;
    const half_t* w2h = (const half_t*)(wsW + 320);
    const half_t* w3h = w2h + 1152;

    const int img = tid >> 7;          // 2 waves per image
    const int t7  = tid & 127;

    // ---- stage image (parity de-interleave, fp32); 128 threads per image
    {
        const int m = mbase + img;
        const int b = m & 255, nn = m >> 8;
        const int t = nn >> 2, dd = nn & 3;
        const float4* s4 = (const float4*)(seq + (((size_t)b * 8 + t) * 4 + dd) * 784);
        for (int i = t7; i < 196; i += 128) {
            float4 v = s4[i];
            int flat = i * 4;
            int r  = flat / 28;
            int cb = flat - r * 28;
            int e  = cb >> 1;
            *(float2*)&s_img2[img][r][e]      = make_float2(v.x, v.z);
            *(float2*)&s_img2[img][r][14 + e] = make_float2(v.y, v.w);
        }
    }
    __syncthreads();

    // ---- stage 1: conv1(1->8)+relu+pool2; item = (img, oc-half, pos), 800 items.
    for (int idx = tid; idx < 800; idx += 512) {
        const int im  = idx / 200;
        const int rem = idx - im * 200;
        const int och = rem / 100;          // oc group: channels och*4..och*4+3 (== g)
        const int pp  = rem - och * 100;
        const int y   = pp / 10;
        const int x   = pp - y * 10;
        const int r0  = 2 * y;
        float p[4][4];
        #pragma unroll
        for (int i = 0; i < 4; i++) {
            const float* rp = &s_img2[im][r0 + i][0];
            p[i][0] = rp[x];
            p[i][1] = rp[14 + x];
            p[i][2] = rp[x + 1];
            p[i][3] = rp[15 + x];
        }
        float res[4];
        #pragma unroll
        for (int cl = 0; cl < 4; cl++) {
            const int c = och * 4 + cl;
            float w[9];
            #pragma unroll
            for (int k = 0; k < 9; k++) w[k] = w1g[c * 9 + k];   // uniform -> s_load
            const float bias = b1g[c];
            float acc = 0.f;
            #pragma unroll
            for (int rr = 0; rr < 2; rr++)
                #pragma unroll
                for (int cc = 0; cc < 2; cc++) {
                    float v = bias;
                    #pragma unroll
                    for (int i = 0; i < 3; i++)
                        #pragma unroll
                        for (int j = 0; j < 3; j++)
                            v += p[rr + i][cc + j] * w[i * 3 + j];
                    acc += fmaxf(v, 0.f);
                }
            res[cl] = 0.25f * acc;
        }
        const int slot = (x >> 1) + 5 * (x & 1);
        h4 o = { (half_t)res[0], (half_t)res[1], (half_t)res[2], (half_t)res[3] };
        *(h4*)&s_p1n[im][och][y][slot][0] = o;
    }
    __syncthreads();

    // ---- stage 2: conv2(8->16)+relu+pool2; thread=(img, pos, oc-pair). 288 dot2/thread.
    {
        const int pos = t7 >> 3;            // 0..15
        const int q2  = t7 & 7;             // oc pair: q2*2, q2*2+1
        const int y   = pos >> 2, x = pos & 3;
        const int r0  = 2 * y;
        const int slotm[4] = { x, 5 + x, x + 1, 6 + x };
        float v[2][4];
        #pragma unroll
        for (int ocl = 0; ocl < 2; ocl++) {
            const float bias = b2g[q2 * 2 + ocl];
            #pragma unroll
            for (int w2 = 0; w2 < 4; w2++) v[ocl][w2] = bias;
        }
        #pragma unroll
        for (int g = 0; g < 2; g++) {
            h2 aL[4][4], aH[4][4];
            #pragma unroll
            for (int i = 0; i < 4; i++)
                #pragma unroll
                for (int dx = 0; dx < 4; dx++) {
                    h4 a = *(const h4*)&s_p1n[img][g][r0 + i][slotm[dx]][0];
                    aL[i][dx] = __builtin_shufflevector(a, a, 0, 1);
                    aH[i][dx] = __builtin_shufflevector(a, a, 2, 3);
                }
            #pragma unroll
            for (int ocl = 0; ocl < 2; ocl++) {
                const int oc = q2 * 2 + ocl;
                h4 wk[9];
                #pragma unroll
                for (int k = 0; k < 9; k++)
                    wk[k] = *(const h4*)&w2h[((k * 2 + g) * 16 + oc) * 4];
                #pragma unroll
                for (int k = 0; k < 9; k++) {
                    const int di = k / 3, dj = k - di * 3;
                    h2 wL = __builtin_shufflevector(wk[k], wk[k], 0, 1);
                    h2 wH = __builtin_shufflevector(wk[k], wk[k], 2, 3);
                    #pragma unroll
                    for (int rr = 0; rr < 2; rr++)
                        #pragma unroll
                        for (int cc = 0; cc < 2; cc++) {
                            float* acc = &v[ocl][rr * 2 + cc];
                            *acc = fdot2f(aL[rr + di][cc + dj], wL, *acc);
                            *acc = fdot2f(aH[rr + di][cc + dj], wH, *acc);
                        }
                }
            }
        }
        float r0v = 0.25f * (fmaxf(v[0][0], 0.f) + fmaxf(v[0][1], 0.f) +
                             fmaxf(v[0][2], 0.f) + fmaxf(v[0][3], 0.f));
        float r1v = 0.25f * (fmaxf(v[1][0], 0.f) + fmaxf(v[1][1], 0.f) +
                             fmaxf(v[1][2], 0.f) + fmaxf(v[1][3], 0.f));
        h2 o = { (half_t)r0v, (half_t)r1v };
        *(h2*)&s_p2n[img][pos][q2 * 2] = o;
    }
    __syncthreads();

    // ---- stage 3: conv3(16->32)+relu; thread=(img, c, u, g-half). 72 dot2/thread.
    {
        const int c  = t7 >> 2;             // 0..31
        const int u  = (t7 >> 1) & 1;
        const int gh = t7 & 1;              // g in {2gh, 2gh+1}
        float acc0 = (gh == 0) ? b3g[c] : 0.f;
        float acc1 = acc0;
        #pragma unroll
        for (int gg = 0; gg < 2; gg++) {
            const int g = gh * 2 + gg;
            h2 AL[3][4], AH[3][4];
            #pragma unroll
            for (int i = 0; i < 3; i++)
                #pragma unroll
                for (int jj = 0; jj < 4; jj++) {
                    h4 a = *(const h4*)&s_p2n[img][(u + i) * 4 + jj][g * 4];
                    AL[i][jj] = __builtin_shufflevector(a, a, 0, 1);
                    AH[i][jj] = __builtin_shufflevector(a, a, 2, 3);
                }
            h4 wk[9];
            #pragma unroll
            for (int k = 0; k < 9; k++)
                wk[k] = *(const h4*)&w3h[((k * 4 + g) * 32 + c) * 4];
            #pragma unroll
            for (int k = 0; k < 9; k++) {
                const int i = k / 3, j = k - i * 3;
                h2 wL = __builtin_shufflevector(wk[k], wk[k], 0, 1);
                h2 wH = __builtin_shufflevector(wk[k], wk[k], 2, 3);
                acc0 = fdot2f(AL[i][j], wL, acc0);
                acc0 = fdot2f(AH[i][j], wH, acc0);
                acc1 = fdot2f(AL[i][j + 1], wL, acc1);
                acc1 = fdot2f(AH[i][j + 1], wH, acc1);
            }
        }
        // merge g-halves (lanes differ in bit0 of tid -> same wave)
        acc0 += __shfl_xor(acc0, 1, 64);
        acc1 += __shfl_xor(acc1, 1, 64);
        float s = fmaxf(acc0, 0.f) + fmaxf(acc1, 0.f);
        s += __shfl_xor(s, 2, 64);          // pool over u
        if ((t7 & 3) == 0) s_p3[img][c] = 0.25f * s;
    }
    __syncthreads();

    // ---- dense + shfl softmax + guards: first wave of each image pair
    if (((tid >> 6) & 1) == 0) {
        const int t6 = tid & 63;
        float logit = -1e30f;
        if (t6 < 10) {
            float acc = bdg[t6];
            #pragma unroll
            for (int c2 = 0; c2 < 32; c2++) acc += s_p3[img][c2] * wdt[c2 * 10 + t6];
            logit = acc;
        }
        float mx = logit;
        #pragma unroll
        for (int s = 1; s < 16; s <<= 1) mx = fmaxf(mx, __shfl_xor(mx, s, 16));
        float e = (t6 < 10) ? __expf(logit - mx) : 0.f;
        float ssum = e;
        #pragma unroll
        for (int s = 1; s < 16; s <<= 1) ssum += __shfl_xor(ssum, s, 16);
        float p = e / ssum;                 // lanes 10..15 -> 0
        const int m = mbase + img;
        if (t6 < 10) out[(size_t)m * 10 + t6] = p;        // all_cnn_preds

        // guards: [p8, p4+p6, p0+p2, p7+p9, p5, p1+p3]; 0xF slot reads lane 15 (p=0)
        const int sh = (t6 < 6 ? t6 : 0) * 4;
        const int ia = (0x157048 >> sh) & 0xF;
        const int ib = (0x3F926F >> sh) & 0xF;
        float pa = __shfl(p, ia, 16);
        float pb = __shfl(p, ib, 16);
        if (t6 < 6)
            out[81920 + (size_t)m * 6 + t6] = pa + pb;    // all_guard_preds
    }
}

// 11 blocks x 256 threads. lane = bb*10 + j inside a wave (6 batches/wave).
// Guards read from `out` (written by cnn). Zero barriers in the 32-step loop.
__global__ __launch_bounds__(256) void sfa_kernel(
    const float* __restrict__ trans,
    const float* __restrict__ out_guards,   // = out (guards at +81920)
    float* __restrict__ out)
{
    __shared__ float M[600];           // [r][i][j]
    const int tid  = threadIdx.x;
    const int lane = tid & 63;
    const int wv   = tid >> 6;

    if (tid < 54) {
        int r = tid / 9, i = tid - r * 9;
        const float* row = trans + (size_t)(r * 9 + i) * 10;
        float x[10], mx = -1e30f;
        #pragma unroll
        for (int j = 0; j < 10; j++) { x[j] = 10.f * row[j]; mx = fmaxf(mx, x[j]); }
        float s = 0.f;
        #pragma unroll
        for (int j = 0; j < 10; j++) { x[j] = __expf(x[j] - mx); s += x[j]; }
        float inv = 1.f / s;
        #pragma unroll
        for (int j = 0; j < 10; j++) M[(r * 9 + i) * 10 + j] = x[j] * inv;
    }
    __syncthreads();

    const int bb    = lane / 10;
    const int j     = lane - bb * 10;
    const int base  = bb * 10;
    const bool ok   = (bb < 6);
    int batch = blockIdx.x * 24 + wv * 6 + bb;
    const bool live = ok && (batch < 256);
    if (!live) batch = 0;

    float Mreg[54];
    #pragma unroll
    for (int k = 0; k < 54; k++) Mreg[k] = M[k * 10 + j];

    float stj = (j == 0) ? 1.f : 0.f;
    const float* gbase = out_guards + 81920;

    for (int nn = 0; nn < 32; nn++) {
        const float* gp = gbase + ((size_t)nn * 256 + batch) * 6;
        float2 ga = *(const float2*)(gp);
        float2 gb = *(const float2*)(gp + 2);
        float2 gc = *(const float2*)(gp + 4);
        float g[6] = {ga.x, ga.y, gb.x, gb.y, gc.x, gc.y};

        float st[10];
        #pragma unroll
        for (int i = 0; i < 10; i++) st[i] = __shfl(stj, base + i, 64);

        float gsum = g[0] + g[1] + g[2] + g[3] + g[4] + g[5];
        float ns = (j == 9) ? gsum * st[9] : 0.f;   // accepting row
        #pragma unroll
        for (int r = 0; r < 6; r++) {
            float h = 0.f;
            #pragma unroll
            for (int i = 0; i < 9; i++) h += st[i] * Mreg[r * 9 + i];
            ns += g[r] * h;
        }
        stj = ns;
    }
    if (live) out[131072 + (size_t)batch * 10 + j] = stj;   // state_final (B,10)
}

extern "C" void kernel_launch(void* const* d_in, const int* in_sizes, int n_in,
                              void* d_out, int out_size, void* d_ws, size_t ws_size,
                              hipStream_t stream) {
    const float* seq = (const float*)d_in[0];
    const float* w1  = (const float*)d_in[1];
    const float* b1  = (const float*)d_in[2];
    const float* w2  = (const float*)d_in[3];
    const float* b2  = (const float*)d_in[4];
    const float* w3  = (const float*)d_in[5];
    const float* b3  = (const float*)d_in[6];
    const float* wd  = (const float*)d_in[7];
    const float* bd  = (const float*)d_in[8];
    const float* tr  = (const float*)d_in[9];
    float* out = (float*)d_out;
    float* wsW = (float*)d_ws;             // wdt fp32 [0,320) + w2h/w3h fp16

    prep_kernel<<<1, 256, 0, stream>>>(w2, w3, wd, wsW);
    cnn_kernel<<<2048, 512, 0, stream>>>(seq, w1, b1, b2, b3, bd, wsW, out);
    sfa_kernel<<<11, 256, 0, stream>>>(tr, out, out);
}

// Round 12
// 139.126 us; speedup vs baseline: 1.1133x; 1.1133x over previous
//
#include <hip/hip_runtime.h>

typedef _Float16 half_t;
typedef _Float16 h2 __attribute__((ext_vector_type(2)));
typedef _Float16 h4 __attribute__((ext_vector_type(4)));

__device__ __forceinline__ float fdot2f(h2 a, h2 b, float c) {
#if __has_builtin(__builtin_amdgcn_fdot2)
    return __builtin_amdgcn_fdot2(a, b, c, false);
#else
    return c + (float)a.x * (float)b.x + (float)a.y * (float)b.y;
#endif
}

// ---- prep: weights -> ws once. ws layout: wdt fp32 [0,320) ; w2h half ; w3h after.
__global__ __launch_bounds__(256) void prep_kernel(
    const float* __restrict__ w2g, const float* __restrict__ w3g,
    const float* __restrict__ wdg, float* __restrict__ wsW)
{
    const int tid = threadIdx.x;
    half_t* w2h = (half_t*)(wsW + 320);
    half_t* w3h = w2h + 1152;
    for (int i = tid; i < 320; i += 256) {             // wdt[c2*10+j] = wd[j][c2]
        int j = i >> 5, c2 = i & 31;
        wsW[c2 * 10 + j] = wdg[i];
    }
    for (int i = tid; i < 1152; i += 256) {            // w2h[((k*2+g)*16+c)*4+l] = w2[c][g*4+l][k]
        int l = i & 3, c = (i >> 2) & 15, g = (i >> 6) & 1, k = i >> 7;
        w2h[i] = (half_t)w2g[(c * 8 + g * 4 + l) * 9 + k];
    }
    for (int i = tid; i < 4608; i += 256) {            // w3h[((k*4+g)*32+c)*4+l] = w3[c][g*4+l][k]
        int l = i & 3, c = (i >> 2) & 31, g = (i >> 7) & 3, k = i >> 9;
        w3h[i] = (half_t)w3g[(c * 16 + g * 4 + l) * 9 + k];
    }
}

// 4 images per block (grid 2048), 256 threads; wave = image for stages 2/3.
// R10 mapping; conv2/conv3 weights staged to LDS (straight copy) — LDS pipe is idle,
// global-weight L1 latency was the stall.
__global__ __launch_bounds__(256, 6) void cnn_kernel(
    const float* __restrict__ seq,
    const float* __restrict__ w1g, const float* __restrict__ b1g,
    const float* __restrict__ b2g, const float* __restrict__ b3g,
    const float* __restrict__ bdg, const float* __restrict__ wsW,
    float* __restrict__ out)
{
    __shared__ __align__(16) float  s_img2[4][28][28];      // parity: [0..13]=even, [14..27]=odd
    __shared__ __align__(16) half_t s_p1n[4][2][10][11][4]; // [img][g][y][slot][l]; ic=g*4+l
    __shared__ __align__(16) half_t s_p2n[4][16][16];       // [img][pixel(y*4+x)][16 ic]
    __shared__ __align__(16) half_t s_w[5760];              // w2h [0,1152) ; w3h [1152,5760)
    __shared__ float s_p3[4][32];

    const int tid   = threadIdx.x;
    const int mbase = blockIdx.x * 4;
    const float* wdt = wsW;

    // ---- stage weights (straight copy of prep-transposed fp16; 720 float4)
    {
        const float4* wsrc = (const float4*)(wsW + 320);
        float4* wdst = (float4*)s_w;
        for (int i = tid; i < 720; i += 256) wdst[i] = wsrc[i];
    }
    // ---- stage images (parity de-interleave, fp32)
    if (tid < 196) {
        #pragma unroll
        for (int img = 0; img < 4; img++) {
            const int m = mbase + img;
            const int b = m & 255, nn = m >> 8;
            const int t = nn >> 2, dd = nn & 3;
            const float4* s4 = (const float4*)(seq + (((size_t)b * 8 + t) * 4 + dd) * 784);
            float4 v = s4[tid];
            int flat = tid * 4;
            int r  = flat / 28;
            int cb = flat - r * 28;       // multiple of 4
            int e  = cb >> 1;
            *(float2*)&s_img2[img][r][e]      = make_float2(v.x, v.z);
            *(float2*)&s_img2[img][r][14 + e] = make_float2(v.y, v.w);
        }
    }
    __syncthreads();

    // ---- stage 1: conv1(1->8)+relu+pool2 at the 100 needed positions/image (400 items).
    for (int idx = tid; idx < 400; idx += 256) {
        const int img = idx / 100;
        const int rem = idx - img * 100;
        const int y   = rem / 10;
        const int x   = rem - y * 10;
        const int r0  = 2 * y;
        float p[4][4];
        #pragma unroll
        for (int i = 0; i < 4; i++) {
            const float* rp = &s_img2[img][r0 + i][0];
            p[i][0] = rp[x];
            p[i][1] = rp[14 + x];
            p[i][2] = rp[x + 1];
            p[i][3] = rp[15 + x];
        }
        float res[8];
        #pragma unroll
        for (int c = 0; c < 8; c++) {
            float w[9];
            #pragma unroll
            for (int k = 0; k < 9; k++) w[k] = w1g[c * 9 + k];   // uniform -> s_load
            const float bias = b1g[c];
            float acc = 0.f;
            #pragma unroll
            for (int rr = 0; rr < 2; rr++)
                #pragma unroll
                for (int cc = 0; cc < 2; cc++) {
                    float v = bias;
                    #pragma unroll
                    for (int i = 0; i < 3; i++)
                        #pragma unroll
                        for (int j = 0; j < 3; j++)
                            v += p[rr + i][cc + j] * w[i * 3 + j];
                    acc += fmaxf(v, 0.f);
                }
            res[c] = 0.25f * acc;
        }
        const int slot = (x >> 1) + 5 * (x & 1);
        h4 lo = { (half_t)res[0], (half_t)res[1], (half_t)res[2], (half_t)res[3] };
        h4 hi = { (half_t)res[4], (half_t)res[5], (half_t)res[6], (half_t)res[7] };
        *(h4*)&s_p1n[img][0][y][slot][0] = lo;
        *(h4*)&s_p1n[img][1][y][slot][0] = hi;
    }
    __syncthreads();

    const int img2 = tid >> 6;          // wave = image
    const int t6   = tid & 63;

    // ---- stage 2: conv2(8->16)+relu+pool2; thread=(img,pos,oc-quad); weights from LDS.
    {
        const int pos = t6 >> 2;
        const int q   = t6 & 3;
        const int y   = pos >> 2, x = pos & 3;
        const int r0  = 2 * y;
        const int slotm[4] = { x, 5 + x, x + 1, 6 + x };
        float v[4][4];
        #pragma unroll
        for (int oc = 0; oc < 4; oc++) {
            const float bias = b2g[q * 4 + oc];
            #pragma unroll
            for (int w2 = 0; w2 < 4; w2++) v[oc][w2] = bias;
        }
        #pragma unroll
        for (int g = 0; g < 2; g++) {
            h2 aL[4][4], aH[4][4];
            #pragma unroll
            for (int i = 0; i < 4; i++)
                #pragma unroll
                for (int dx = 0; dx < 4; dx++) {
                    h4 a = *(const h4*)&s_p1n[img2][g][r0 + i][slotm[dx]][0];
                    aL[i][dx] = __builtin_shufflevector(a, a, 0, 1);
                    aH[i][dx] = __builtin_shufflevector(a, a, 2, 3);
                }
            #pragma unroll
            for (int oc = 0; oc < 4; oc++) {
                h4 wk[9];
                #pragma unroll
                for (int k = 0; k < 9; k++)
                    wk[k] = *(const h4*)&s_w[((k * 2 + g) * 16 + q * 4 + oc) * 4];
                #pragma unroll
                for (int k = 0; k < 9; k++) {
                    const int di = k / 3, dj = k - di * 3;
                    h2 wL = __builtin_shufflevector(wk[k], wk[k], 0, 1);
                    h2 wH = __builtin_shufflevector(wk[k], wk[k], 2, 3);
                    #pragma unroll
                    for (int rr = 0; rr < 2; rr++)
                        #pragma unroll
                        for (int cc = 0; cc < 2; cc++) {
                            float* acc = &v[oc][rr * 2 + cc];
                            *acc = fdot2f(aL[rr + di][cc + dj], wL, *acc);
                            *acc = fdot2f(aH[rr + di][cc + dj], wH, *acc);
                        }
                }
            }
        }
        float res[4];
        #pragma unroll
        for (int oc = 0; oc < 4; oc++)
            res[oc] = 0.25f * (fmaxf(v[oc][0], 0.f) + fmaxf(v[oc][1], 0.f) +
                               fmaxf(v[oc][2], 0.f) + fmaxf(v[oc][3], 0.f));
        h4 o = { (half_t)res[0], (half_t)res[1], (half_t)res[2], (half_t)res[3] };
        *(h4*)&s_p2n[img2][pos][q * 4] = o;
    }
    __syncthreads();

    // ---- stage 3: conv3(16->32)+relu; thread=(img,c,u), windows v=0,1; weights from LDS.
    {
        const int c = t6 >> 1;
        const int u = t6 & 1;
        float acc0 = b3g[c], acc1 = acc0;
        #pragma unroll
        for (int g = 0; g < 4; g++) {
            h2 AL[3][4], AH[3][4];
            #pragma unroll
            for (int i = 0; i < 3; i++)
                #pragma unroll
                for (int jj = 0; jj < 4; jj++) {
                    h4 a = *(const h4*)&s_p2n[img2][(u + i) * 4 + jj][g * 4];
                    AL[i][jj] = __builtin_shufflevector(a, a, 0, 1);
                    AH[i][jj] = __builtin_shufflevector(a, a, 2, 3);
                }
            h4 wk[9];
            #pragma unroll
            for (int k = 0; k < 9; k++)
                wk[k] = *(const h4*)&s_w[1152 + ((k * 4 + g) * 32 + c) * 4];
            #pragma unroll
            for (int k = 0; k < 9; k++) {
                const int i = k / 3, j = k - i * 3;
                h2 wL = __builtin_shufflevector(wk[k], wk[k], 0, 1);
                h2 wH = __builtin_shufflevector(wk[k], wk[k], 2, 3);
                acc0 = fdot2f(AL[i][j], wL, acc0);
                acc0 = fdot2f(AH[i][j], wH, acc0);
                acc1 = fdot2f(AL[i][j + 1], wL, acc1);
                acc1 = fdot2f(AH[i][j + 1], wH, acc1);
            }
        }
        float s = fmaxf(acc0, 0.f) + fmaxf(acc1, 0.f);
        s += __shfl_xor(s, 1, 64);                 // partner u^1
        if (u == 0) s_p3[img2][c] = 0.25f * s;     // lane c -> bank c, conflict-free
    }
    __syncthreads();

    // ---- dense + shfl softmax + guards (no more barriers)
    {
        float logit = -1e30f;
        if (t6 < 10) {
            float acc = bdg[t6];
            #pragma unroll
            for (int c2 = 0; c2 < 32; c2++) acc += s_p3[img2][c2] * wdt[c2 * 10 + t6];
            logit = acc;
        }
        float mx = logit;
        #pragma unroll
        for (int s = 1; s < 16; s <<= 1) mx = fmaxf(mx, __shfl_xor(mx, s, 16));
        float e = (t6 < 10) ? __expf(logit - mx) : 0.f;
        float ssum = e;
        #pragma unroll
        for (int s = 1; s < 16; s <<= 1) ssum += __shfl_xor(ssum, s, 16);
        float p = e / ssum;                        // lanes 10..15 -> p = 0
        const int m = mbase + img2;
        if (t6 < 10) out[(size_t)m * 10 + t6] = p; // all_cnn_preds (N,B,10)

        // guards: [p8, p4+p6, p0+p2, p7+p9, p5, p1+p3]; 0xF slot reads lane 15 (p=0)
        const int sh = (t6 < 6 ? t6 : 0) * 4;
        const int ia = (0x157048 >> sh) & 0xF;
        const int ib = (0x3F926F >> sh) & 0xF;
        float pa = __shfl(p, ia, 16);
        float pb = __shfl(p, ib, 16);
        if (t6 < 6)
            out[81920 + (size_t)m * 6 + t6] = pa + pb;    // all_guard_preds (N,B,6)
    }
}

// 11 blocks x 256 threads. lane = bb*10 + j inside a wave (6 batches/wave).
// Guards read from `out` (written by cnn). Zero barriers in the 32-step loop.
__global__ __launch_bounds__(256) void sfa_kernel(
    const float* __restrict__ trans,
    const float* __restrict__ out_guards,   // = out (guards at +81920)
    float* __restrict__ out)
{
    __shared__ float M[600];           // [r][i][j]
    const int tid  = threadIdx.x;
    const int lane = tid & 63;
    const int wv   = tid >> 6;

    if (tid < 54) {
        int r = tid / 9, i = tid - r * 9;
        const float* row = trans + (size_t)(r * 9 + i) * 10;
        float x[10], mx = -1e30f;
        #pragma unroll
        for (int j = 0; j < 10; j++) { x[j] = 10.f * row[j]; mx = fmaxf(mx, x[j]); }
        float s = 0.f;
        #pragma unroll
        for (int j = 0; j < 10; j++) { x[j] = __expf(x[j] - mx); s += x[j]; }
        float inv = 1.f / s;
        #pragma unroll
        for (int j = 0; j < 10; j++) M[(r * 9 + i) * 10 + j] = x[j] * inv;
    }
    __syncthreads();

    const int bb    = lane / 10;
    const int j     = lane - bb * 10;
    const int base  = bb * 10;
    const bool ok   = (bb < 6);
    int batch = blockIdx.x * 24 + wv * 6 + bb;
    const bool live = ok && (batch < 256);
    if (!live) batch = 0;

    float Mreg[54];
    #pragma unroll
    for (int k = 0; k < 54; k++) Mreg[k] = M[k * 10 + j];

    float stj = (j == 0) ? 1.f : 0.f;
    const float* gbase = out_guards + 81920;

    for (int nn = 0; nn < 32; nn++) {
        const float* gp = gbase + ((size_t)nn * 256 + batch) * 6;
        float2 ga = *(const float2*)(gp);
        float2 gb = *(const float2*)(gp + 2);
        float2 gc = *(const float2*)(gp + 4);
        float g[6] = {ga.x, ga.y, gb.x, gb.y, gc.x, gc.y};

        float st[10];
        #pragma unroll
        for (int i = 0; i < 10; i++) st[i] = __shfl(stj, base + i, 64);

        float gsum = g[0] + g[1] + g[2] + g[3] + g[4] + g[5];
        float ns = (j == 9) ? gsum * st[9] : 0.f;   // accepting row
        #pragma unroll
        for (int r = 0; r < 6; r++) {
            float h = 0.f;
            #pragma unroll
            for (int i = 0; i < 9; i++) h += st[i] * Mreg[r * 9 + i];
            ns += g[r] * h;
        }
        stj = ns;
    }
    if (live) out[131072 + (size_t)batch * 10 + j] = stj;   // state_final (B,10)
}

extern "C" void kernel_launch(void* const* d_in, const int* in_sizes, int n_in,
                              void* d_out, int out_size, void* d_ws, size_t ws_size,
                              hipStream_t stream) {
    const float* seq = (const float*)d_in[0];
    const float* w1  = (const float*)d_in[1];
    const float* b1  = (const float*)d_in[2];
    const float* w2  = (const float*)d_in[3];
    const float* b2  = (const float*)d_in[4];
    const float* w3  = (const float*)d_in[5];
    const float* b3  = (const float*)d_in[6];
    const float* wd  = (const float*)d_in[7];
    const float* bd  = (const float*)d_in[8];
    const float* tr  = (const float*)d_in[9];
    float* out = (float*)d_out;
    float* wsW = (float*)d_ws;             // wdt fp32 [0,320) + w2h/w3h fp16

    prep_kernel<<<1, 256, 0, stream>>>(w2, w3, wd, wsW);
    cnn_kernel<<<2048, 256, 0, stream>>>(seq, w1, b1, b2, b3, bd, wsW, out);
    sfa_kernel<<<11, 256, 0, stream>>>(tr, out, out);
}

// Round 13
// 136.123 us; speedup vs baseline: 1.1379x; 1.0221x over previous
//
#include <hip/hip_runtime.h>

typedef _Float16 half_t;
typedef _Float16 h2 __attribute__((ext_vector_type(2)));
typedef _Float16 h4 __attribute__((ext_vector_type(4)));
typedef _Float16 f16x8 __attribute__((ext_vector_type(8)));
typedef float f32x4 __attribute__((ext_vector_type(4)));

__device__ __forceinline__ float fdot2f(h2 a, h2 b, float c) {
#if __has_builtin(__builtin_amdgcn_fdot2)
    return __builtin_amdgcn_fdot2(a, b, c, false);
#else
    return c + (float)a.x * (float)b.x + (float)a.y * (float)b.y;
#endif
}

// ws layout (floats): wdt [0,320) ; w3h halves at +320 (4608 h = 2304 f) -> [320,2624) ;
// w2B MFMA B-fragments at +2624 (1536 h = 768 f) -> [2624,3392)
__global__ __launch_bounds__(256) void prep_kernel(
    const float* __restrict__ w2g, const float* __restrict__ w3g,
    const float* __restrict__ wdg, float* __restrict__ wsW)
{
    const int tid = threadIdx.x;
    half_t* w3h = (half_t*)(wsW + 320);
    half_t* w2B = (half_t*)(wsW + 2624);
    for (int i = tid; i < 320; i += 256) {             // wdt[c2*10+j] = wd[j][c2]
        int j = i >> 5, c2 = i & 31;
        wsW[c2 * 10 + j] = wdg[i];
    }
    for (int i = tid; i < 4608; i += 256) {            // w3h[((k*4+g)*32+c)*4+l] = w3[c][g*4+l][k]
        int l = i & 3, c = (i >> 2) & 31, g = (i >> 7) & 3, k = i >> 9;
        w3h[i] = (half_t)w3g[(c * 16 + g * 4 + l) * 9 + k];
    }
    // B-fragments for mfma_f32_16x16x32_f16: lane holds B[k = c*32 + (lane>>4)*8 + j][n = lane&15]
    // with k = (g*9 + tap)*4 + l, value = w2[oc=n][ic=g*4+l][tap]; k>=72 -> 0 (pad).
    for (int i = tid; i < 1536; i += 256) {
        int c    = i >> 9;
        int r    = i & 511;
        int lane = r >> 3;
        int j    = r & 7;
        int k    = c * 32 + ((lane >> 4) << 3) + j;
        half_t val = (half_t)0.f;
        if (k < 72) {
            int t = k >> 2, l = k & 3;
            int g = (t >= 9) ? 1 : 0;
            int tap = t - 9 * g;
            int oc  = lane & 15;
            val = (half_t)w2g[(oc * 8 + g * 4 + l) * 9 + tap];
        }
        w2B[i] = val;
    }
}

// 4 images per block (grid 2048), 256 threads; wave = image for stages 2/3.
// Stage 2 = per-wave MFMA GEMM (M=64 conv pos, N=16 oc, K=72), 12 mfma/image.
__global__ __launch_bounds__(256, 4) void cnn_kernel(
    const float* __restrict__ seq,
    const float* __restrict__ w1g, const float* __restrict__ b1g,
    const float* __restrict__ b2g, const float* __restrict__ b3g,
    const float* __restrict__ bdg, const float* __restrict__ wsW,
    float* __restrict__ out)
{
    __shared__ __align__(16) float  s_img2[4][28][28];      // parity: [0..13]=even, [14..27]=odd
    __shared__ __align__(16) half_t s_p1n[4][2][10][11][4]; // [img][g][y][slot][l]; ic=g*4+l
    __shared__ __align__(16) half_t s_p2n[4][16][16];       // [img][pixel(y*4+x)][16 ic]
    __shared__ __align__(16) half_t s_w[4608];              // w3h
    __shared__ float s_p3[4][32];

    const int tid   = threadIdx.x;
    const int mbase = blockIdx.x * 4;
    const float*  wdt = wsW;
    const half_t* w2B = (const half_t*)(wsW + 2624);

    // ---- stage weights (straight copy of prep-transposed w3 fp16; 576 float4)
    {
        const float4* wsrc = (const float4*)(wsW + 320);
        float4* wdst = (float4*)s_w;
        for (int i = tid; i < 576; i += 256) wdst[i] = wsrc[i];
    }
    // ---- stage images (parity de-interleave, fp32)
    if (tid < 196) {
        #pragma unroll
        for (int img = 0; img < 4; img++) {
            const int m = mbase + img;
            const int b = m & 255, nn = m >> 8;
            const int t = nn >> 2, dd = nn & 3;
            const float4* s4 = (const float4*)(seq + (((size_t)b * 8 + t) * 4 + dd) * 784);
            float4 v = s4[tid];
            int flat = tid * 4;
            int r  = flat / 28;
            int cb = flat - r * 28;
            int e  = cb >> 1;
            *(float2*)&s_img2[img][r][e]      = make_float2(v.x, v.z);
            *(float2*)&s_img2[img][r][14 + e] = make_float2(v.y, v.w);
        }
    }
    __syncthreads();

    // ---- stage 1: conv1(1->8)+relu+pool2 at the 100 needed positions/image (400 items).
    for (int idx = tid; idx < 400; idx += 256) {
        const int img = idx / 100;
        const int rem = idx - img * 100;
        const int y   = rem / 10;
        const int x   = rem - y * 10;
        const int r0  = 2 * y;
        float p[4][4];
        #pragma unroll
        for (int i = 0; i < 4; i++) {
            const float* rp = &s_img2[img][r0 + i][0];
            p[i][0] = rp[x];
            p[i][1] = rp[14 + x];
            p[i][2] = rp[x + 1];
            p[i][3] = rp[15 + x];
        }
        float res[8];
        #pragma unroll
        for (int c = 0; c < 8; c++) {
            float w[9];
            #pragma unroll
            for (int k = 0; k < 9; k++) w[k] = w1g[c * 9 + k];   // uniform -> s_load
            const float bias = b1g[c];
            float acc = 0.f;
            #pragma unroll
            for (int rr = 0; rr < 2; rr++)
                #pragma unroll
                for (int cc = 0; cc < 2; cc++) {
                    float v = bias;
                    #pragma unroll
                    for (int i = 0; i < 3; i++)
                        #pragma unroll
                        for (int j = 0; j < 3; j++)
                            v += p[rr + i][cc + j] * w[i * 3 + j];
                    acc += fmaxf(v, 0.f);
                }
            res[c] = 0.25f * acc;
        }
        const int slot = (x >> 1) + 5 * (x & 1);
        h4 lo = { (half_t)res[0], (half_t)res[1], (half_t)res[2], (half_t)res[3] };
        h4 hi = { (half_t)res[4], (half_t)res[5], (half_t)res[6], (half_t)res[7] };
        *(h4*)&s_p1n[img][0][y][slot][0] = lo;
        *(h4*)&s_p1n[img][1][y][slot][0] = hi;
    }
    __syncthreads();

    const int img2 = tid >> 6;          // wave = image
    const int t6   = tid & 63;

    // ---- stage 2 (MFMA): conv2 at 8x8 conv grid + relu + pool -> s_p2n.
    // K = 72: k = (g*9 + i*3+jj)*4 + l. A[m][k] = p1[g][cy+i][cx+jj][l], m=cy*8+cx.
    {
        const int q  = t6 >> 4;
        const int oc = t6 & 15;
        // decode lane's 2 taps per chunk (tile-independent)
        int tg[6], ti[6], tj[6];
        bool tv[6];
        #pragma unroll
        for (int c = 0; c < 3; c++)
            #pragma unroll
            for (int s = 0; s < 2; s++) {
                int e = c * 2 + s;
                int t = c * 8 + q * 2 + s;
                bool v = (t < 18);
                int tt = v ? t : 0;
                int g = (tt >= 9) ? 1 : 0;
                int tap = tt - 9 * g;
                tg[e] = g; ti[e] = tap / 3; tj[e] = tap - 3 * (tap / 3); tv[e] = v;
            }
        f16x8 B[3];
        #pragma unroll
        for (int c = 0; c < 3; c++)
            B[c] = *(const f16x8*)&w2B[(c * 64 + t6) * 8];

        const float bias = b2g[oc];
        f32x4 acc[4];
        #pragma unroll
        for (int T = 0; T < 4; T++) {
            acc[T][0] = bias; acc[T][1] = bias; acc[T][2] = bias; acc[T][3] = bias;
        }
        const int mm = t6 & 15;
        #pragma unroll
        for (int T = 0; T < 4; T++) {
            const int cy = 2 * T + (mm >> 3);
            const int cx = mm & 7;
            #pragma unroll
            for (int c = 0; c < 3; c++) {
                h4 a0, a1;
                a0[0]=a0[1]=a0[2]=a0[3]=(half_t)0.f;
                a1[0]=a1[1]=a1[2]=a1[3]=(half_t)0.f;
                const int e0 = c * 2, e1 = c * 2 + 1;
                if (tv[e0]) {
                    int col = cx + tj[e0];
                    int slot = (col >> 1) + 5 * (col & 1);
                    a0 = *(const h4*)&s_p1n[img2][tg[e0]][cy + ti[e0]][slot][0];
                }
                if (tv[e1]) {
                    int col = cx + tj[e1];
                    int slot = (col >> 1) + 5 * (col & 1);
                    a1 = *(const h4*)&s_p1n[img2][tg[e1]][cy + ti[e1]][slot][0];
                }
                f16x8 A = __builtin_shufflevector(a0, a1, 0, 1, 2, 3, 4, 5, 6, 7);
                acc[T] = __builtin_amdgcn_mfma_f32_16x16x32_f16(A, B[c], acc[T], 0, 0, 0);
            }
        }
        // epilogue: lane q holds rows q*4+reg (cy = 2T + (q>>1), cx = (q&1)*4 + reg)
        #pragma unroll
        for (int T = 0; T < 4; T++) {
            float p0 = fmaxf(acc[T][0], 0.f) + fmaxf(acc[T][1], 0.f);
            float p1 = fmaxf(acc[T][2], 0.f) + fmaxf(acc[T][3], 0.f);
            p0 += __shfl_xor(p0, 32, 64);          // pool over cy (q ^ 2)
            p1 += __shfl_xor(p1, 32, 64);
            if (q < 2) {                           // px = q*2 + {0,1}, py = T
                s_p2n[img2][T * 4 + q * 2    ][oc] = (half_t)(0.25f * p0);
                s_p2n[img2][T * 4 + q * 2 + 1][oc] = (half_t)(0.25f * p1);
            }
        }
    }
    __syncthreads();

    // ---- stage 3: conv3(16->32)+relu; thread=(img,c,u), windows v=0,1; weights from LDS.
    {
        const int c = t6 >> 1;
        const int u = t6 & 1;
        float acc0 = b3g[c], acc1 = acc0;
        #pragma unroll
        for (int g = 0; g < 4; g++) {
            h2 AL[3][4], AH[3][4];
            #pragma unroll
            for (int i = 0; i < 3; i++)
                #pragma unroll
                for (int jj = 0; jj < 4; jj++) {
                    h4 a = *(const h4*)&s_p2n[img2][(u + i) * 4 + jj][g * 4];
                    AL[i][jj] = __builtin_shufflevector(a, a, 0, 1);
                    AH[i][jj] = __builtin_shufflevector(a, a, 2, 3);
                }
            h4 wk[9];
            #pragma unroll
            for (int k = 0; k < 9; k++)
                wk[k] = *(const h4*)&s_w[((k * 4 + g) * 32 + c) * 4];
            #pragma unroll
            for (int k = 0; k < 9; k++) {
                const int i = k / 3, j = k - i * 3;
                h2 wL = __builtin_shufflevector(wk[k], wk[k], 0, 1);
                h2 wH = __builtin_shufflevector(wk[k], wk[k], 2, 3);
                acc0 = fdot2f(AL[i][j], wL, acc0);
                acc0 = fdot2f(AH[i][j], wH, acc0);
                acc1 = fdot2f(AL[i][j + 1], wL, acc1);
                acc1 = fdot2f(AH[i][j + 1], wH, acc1);
            }
        }
        float s = fmaxf(acc0, 0.f) + fmaxf(acc1, 0.f);
        s += __shfl_xor(s, 1, 64);                 // partner u^1
        if (u == 0) s_p3[img2][c] = 0.25f * s;
    }
    __syncthreads();

    // ---- dense + shfl softmax + guards
    {
        float logit = -1e30f;
        if (t6 < 10) {
            float acc = bdg[t6];
            #pragma unroll
            for (int c2 = 0; c2 < 32; c2++) acc += s_p3[img2][c2] * wdt[c2 * 10 + t6];
            logit = acc;
        }
        float mx = logit;
        #pragma unroll
        for (int s = 1; s < 16; s <<= 1) mx = fmaxf(mx, __shfl_xor(mx, s, 16));
        float e = (t6 < 10) ? __expf(logit - mx) : 0.f;
        float ssum = e;
        #pragma unroll
        for (int s = 1; s < 16; s <<= 1) ssum += __shfl_xor(ssum, s, 16);
        float p = e / ssum;                        // lanes 10..15 -> p = 0
        const int m = mbase + img2;
        if (t6 < 10) out[(size_t)m * 10 + t6] = p; // all_cnn_preds (N,B,10)

        // guards: [p8, p4+p6, p0+p2, p7+p9, p5, p1+p3]; 0xF slot reads lane 15 (p=0)
        const int sh = (t6 < 6 ? t6 : 0) * 4;
        const int ia = (0x157048 >> sh) & 0xF;
        const int ib = (0x3F926F >> sh) & 0xF;
        float pa = __shfl(p, ia, 16);
        float pb = __shfl(p, ib, 16);
        if (t6 < 6)
            out[81920 + (size_t)m * 6 + t6] = pa + pb;    // all_guard_preds (N,B,6)
    }
}

// 11 blocks x 256 threads. lane = bb*10 + j inside a wave (6 batches/wave).
__global__ __launch_bounds__(256) void sfa_kernel(
    const float* __restrict__ trans,
    const float* __restrict__ out_guards,   // = out (guards at +81920)
    float* __restrict__ out)
{
    __shared__ float M[600];           // [r][i][j]
    const int tid  = threadIdx.x;
    const int lane = tid & 63;
    const int wv   = tid >> 6;

    if (tid < 54) {
        int r = tid / 9, i = tid - r * 9;
        const float* row = trans + (size_t)(r * 9 + i) * 10;
        float x[10], mx = -1e30f;
        #pragma unroll
        for (int j = 0; j < 10; j++) { x[j] = 10.f * row[j]; mx = fmaxf(mx, x[j]); }
        float s = 0.f;
        #pragma unroll
        for (int j = 0; j < 10; j++) { x[j] = __expf(x[j] - mx); s += x[j]; }
        float inv = 1.f / s;
        #pragma unroll
        for (int j = 0; j < 10; j++) M[(r * 9 + i) * 10 + j] = x[j] * inv;
    }
    __syncthreads();

    const int bb    = lane / 10;
    const int j     = lane - bb * 10;
    const int base  = bb * 10;
    const bool ok   = (bb < 6);
    int batch = blockIdx.x * 24 + wv * 6 + bb;
    const bool live = ok && (batch < 256);
    if (!live) batch = 0;

    float Mreg[54];
    #pragma unroll
    for (int k = 0; k < 54; k++) Mreg[k] = M[k * 10 + j];

    float stj = (j == 0) ? 1.f : 0.f;
    const float* gbase = out_guards + 81920;

    for (int nn = 0; nn < 32; nn++) {
        const float* gp = gbase + ((size_t)nn * 256 + batch) * 6;
        float2 ga = *(const float2*)(gp);
        float2 gb = *(const float2*)(gp + 2);
        float2 gc = *(const float2*)(gp + 4);
        float g[6] = {ga.x, ga.y, gb.x, gb.y, gc.x, gc.y};

        float st[10];
        #pragma unroll
        for (int i = 0; i < 10; i++) st[i] = __shfl(stj, base + i, 64);

        float gsum = g[0] + g[1] + g[2] + g[3] + g[4] + g[5];
        float ns = (j == 9) ? gsum * st[9] : 0.f;   // accepting row
        #pragma unroll
        for (int r = 0; r < 6; r++) {
            float h = 0.f;
            #pragma unroll
            for (int i = 0; i < 9; i++) h += st[i] * Mreg[r * 9 + i];
            ns += g[r] * h;
        }
        stj = ns;
    }
    if (live) out[131072 + (size_t)batch * 10 + j] = stj;   // state_final (B,10)
}

extern "C" void kernel_launch(void* const* d_in, const int* in_sizes, int n_in,
                              void* d_out, int out_size, void* d_ws, size_t ws_size,
                              hipStream_t stream) {
    const float* seq = (const float*)d_in[0];
    const float* w1  = (const float*)d_in[1];
    const float* b1  = (const float*)d_in[2];
    const float* w2  = (const float*)d_in[3];
    const float* b2  = (const float*)d_in[4];
    const float* w3  = (const float*)d_in[5];
    const float* b3  = (const float*)d_in[6];
    const float* wd  = (const float*)d_in[7];
    const float* bd  = (const float*)d_in[8];
    const float* tr  = (const float*)d_in[9];
    float* out = (float*)d_out;
    float* wsW = (float*)d_ws;             // wdt + w3h + w2B fragments

    prep_kernel<<<1, 256, 0, stream>>>(w2, w3, wd, wsW);
    cnn_kernel<<<2048, 256, 0, stream>>>(seq, w1, b1, b2, b3, bd, wsW, out);
    sfa_kernel<<<11, 256, 0, stream>>>(tr, out, out);
}

// Round 15
// 132.020 us; speedup vs baseline: 1.1733x; 1.0311x over previous
//
#include <hip/hip_runtime.h>

typedef _Float16 half_t;
typedef _Float16 h2 __attribute__((ext_vector_type(2)));
typedef _Float16 h4 __attribute__((ext_vector_type(4)));
typedef _Float16 f16x8 __attribute__((ext_vector_type(8)));
typedef float f32x4 __attribute__((ext_vector_type(4)));

// ws layout (floats): wdt [0,320) ; w2B halves at +320 (1536 h = 768 f) -> [320,1088) ;
// w3B halves at +1088 (5120 h = 2560 f) -> [1088,3648)
__global__ __launch_bounds__(256) void prep_kernel(
    const float* __restrict__ w2g, const float* __restrict__ w3g,
    const float* __restrict__ wdg, float* __restrict__ wsW)
{
    const int tid = threadIdx.x;
    half_t* w2B = (half_t*)(wsW + 320);
    half_t* w3B = (half_t*)(wsW + 1088);
    for (int i = tid; i < 320; i += 256) {             // wdt[c2*10+j] = wd[j][c2]
        int j = i >> 5, c2 = i & 31;
        wsW[c2 * 10 + j] = wdg[i];
    }
    // stage-2 B-fragments (mfma 16x16x32): lane holds B[k=c*32+(lane>>4)*8+j][n=lane&15]
    // k = (g*9+tap)*4 + l ; value = w2[oc=n][ic=g*4+l][tap] ; k>=72 -> 0
    for (int i = tid; i < 1536; i += 256) {
        int c    = i >> 9;
        int r    = i & 511;
        int lane = r >> 3;
        int j    = r & 7;
        int k    = c * 32 + ((lane >> 4) << 3) + j;
        half_t val = (half_t)0.f;
        if (k < 72) {
            int t = k >> 2, l = k & 3;
            int g = (t >= 9) ? 1 : 0;
            int tap = t - 9 * g;
            int oc  = lane & 15;
            val = (half_t)w2g[(oc * 8 + g * 4 + l) * 9 + tap];
        }
        w2B[i] = val;
    }
    // stage-3 B-fragments: GEMM M=16(img*4+win), N=16/tile (oc=tile*16+n), K=144 (k=tap*16+ic)
    // index = ((tile*5 + c)*64 + lane)*8 + j ; k = c*32+(lane>>4)*8+j ; k>=144 -> 0
    for (int i = tid; i < 5120; i += 256) {
        int j    = i & 7;
        int lane = (i >> 3) & 63;
        int tc   = i >> 9;            // 0..9
        int tile = tc / 5;
        int c    = tc - tile * 5;
        int k    = c * 32 + ((lane >> 4) << 3) + j;
        int n    = lane & 15;
        half_t val = (half_t)0.f;
        if (k < 144) {
            int ic = k & 15, tap = k >> 4;
            val = (half_t)w3g[((tile * 16 + n) * 16 + ic) * 9 + tap];
        }
        w3B[i] = val;
    }
}

// 4 images per block (grid 2048), 256 threads; wave = image for stage 2.
// Stage 2: per-wave MFMA GEMM (M=64 pos, N=16 oc, K=72).
// Stage 3: block-level MFMA GEMM (M=16 = 4img x 4win, N=32 oc over 2 wave-tiles, K=144).
__global__ __launch_bounds__(256, 6) void cnn_kernel(
    const float* __restrict__ seq,
    const float* __restrict__ w1g, const float* __restrict__ b1g,
    const float* __restrict__ b2g, const float* __restrict__ b3g,
    const float* __restrict__ bdg, const float* __restrict__ wsW,
    float* __restrict__ out)
{
    __shared__ __align__(16) float  s_img2[4][28][28];      // parity: [0..13]=even, [14..27]=odd
    __shared__ __align__(16) half_t s_p1n[4][2][10][11][4]; // [img][g][y][slot][l]; ic=g*4+l
    __shared__ __align__(16) half_t s_p2n[4][16][16];       // [img][pixel(y*4+x)][16 ic]
    __shared__ float s_p3[4][32];

    const int tid   = threadIdx.x;
    const int mbase = blockIdx.x * 4;
    const float*  wdt = wsW;
    const half_t* w2B = (const half_t*)(wsW + 320);
    const half_t* w3B = (const half_t*)(wsW + 1088);

    // ---- stage images (parity de-interleave, fp32)
    if (tid < 196) {
        #pragma unroll
        for (int img = 0; img < 4; img++) {
            const int m = mbase + img;
            const int b = m & 255, nn = m >> 8;
            const int t = nn >> 2, dd = nn & 3;
            const float4* s4 = (const float4*)(seq + (((size_t)b * 8 + t) * 4 + dd) * 784);
            float4 v = s4[tid];
            int flat = tid * 4;
            int r  = flat / 28;
            int cb = flat - r * 28;
            int e  = cb >> 1;
            *(float2*)&s_img2[img][r][e]      = make_float2(v.x, v.z);
            *(float2*)&s_img2[img][r][14 + e] = make_float2(v.y, v.w);
        }
    }
    __syncthreads();

    // ---- stage 1: conv1(1->8)+relu+pool2 at the 100 needed positions/image (400 items).
    for (int idx = tid; idx < 400; idx += 256) {
        const int img = idx / 100;
        const int rem = idx - img * 100;
        const int y   = rem / 10;
        const int x   = rem - y * 10;
        const int r0  = 2 * y;
        float p[4][4];
        #pragma unroll
        for (int i = 0; i < 4; i++) {
            const float* rp = &s_img2[img][r0 + i][0];
            p[i][0] = rp[x];
            p[i][1] = rp[14 + x];
            p[i][2] = rp[x + 1];
            p[i][3] = rp[15 + x];
        }
        float res[8];
        #pragma unroll
        for (int c = 0; c < 8; c++) {
            float w[9];
            #pragma unroll
            for (int k = 0; k < 9; k++) w[k] = w1g[c * 9 + k];   // uniform -> s_load
            const float bias = b1g[c];
            float acc = 0.f;
            #pragma unroll
            for (int rr = 0; rr < 2; rr++)
                #pragma unroll
                for (int cc = 0; cc < 2; cc++) {
                    float v = bias;
                    #pragma unroll
                    for (int i = 0; i < 3; i++)
                        #pragma unroll
                        for (int j = 0; j < 3; j++)
                            v += p[rr + i][cc + j] * w[i * 3 + j];
                    acc += fmaxf(v, 0.f);
                }
            res[c] = 0.25f * acc;
        }
        const int slot = (x >> 1) + 5 * (x & 1);
        h4 lo = { (half_t)res[0], (half_t)res[1], (half_t)res[2], (half_t)res[3] };
        h4 hi = { (half_t)res[4], (half_t)res[5], (half_t)res[6], (half_t)res[7] };
        *(h4*)&s_p1n[img][0][y][slot][0] = lo;
        *(h4*)&s_p1n[img][1][y][slot][0] = hi;
    }
    __syncthreads();

    const int img2 = tid >> 6;          // wave = image (stage 2)
    const int t6   = tid & 63;

    // ---- stage 2 (MFMA): conv2 at 8x8 conv grid + relu + pool -> s_p2n.
    {
        const int q  = t6 >> 4;
        const int oc = t6 & 15;
        int tg[6], ti[6], tj[6];
        bool tv[6];
        #pragma unroll
        for (int c = 0; c < 3; c++)
            #pragma unroll
            for (int s = 0; s < 2; s++) {
                int e = c * 2 + s;
                int t = c * 8 + q * 2 + s;
                bool v = (t < 18);
                int tt = v ? t : 0;
                int g = (tt >= 9) ? 1 : 0;
                int tap = tt - 9 * g;
                tg[e] = g; ti[e] = tap / 3; tj[e] = tap - 3 * (tap / 3); tv[e] = v;
            }
        f16x8 B[3];
        #pragma unroll
        for (int c = 0; c < 3; c++)
            B[c] = *(const f16x8*)&w2B[(c * 64 + t6) * 8];

        const float bias = b2g[oc];
        f32x4 acc[4];
        #pragma unroll
        for (int T = 0; T < 4; T++) {
            acc[T][0] = bias; acc[T][1] = bias; acc[T][2] = bias; acc[T][3] = bias;
        }
        const int mm = t6 & 15;
        #pragma unroll
        for (int T = 0; T < 4; T++) {
            const int cy = 2 * T + (mm >> 3);
            const int cx = mm & 7;
            #pragma unroll
            for (int c = 0; c < 3; c++) {
                h4 a0, a1;
                #pragma unroll
                for (int z = 0; z < 4; z++) { a0[z] = (half_t)0.f; a1[z] = (half_t)0.f; }
                const int e0 = c * 2, e1 = c * 2 + 1;
                if (tv[e0]) {
                    int col = cx + tj[e0];
                    int slot = (col >> 1) + 5 * (col & 1);
                    a0 = *(const h4*)&s_p1n[img2][tg[e0]][cy + ti[e0]][slot][0];
                }
                if (tv[e1]) {
                    int col = cx + tj[e1];
                    int slot = (col >> 1) + 5 * (col & 1);
                    a1 = *(const h4*)&s_p1n[img2][tg[e1]][cy + ti[e1]][slot][0];
                }
                f16x8 A = __builtin_shufflevector(a0, a1, 0, 1, 2, 3, 4, 5, 6, 7);
                acc[T] = __builtin_amdgcn_mfma_f32_16x16x32_f16(A, B[c], acc[T], 0, 0, 0);
            }
        }
        #pragma unroll
        for (int T = 0; T < 4; T++) {
            float p0 = fmaxf(acc[T][0], 0.f) + fmaxf(acc[T][1], 0.f);
            float p1 = fmaxf(acc[T][2], 0.f) + fmaxf(acc[T][3], 0.f);
            p0 += __shfl_xor(p0, 32, 64);          // pool over cy
            p1 += __shfl_xor(p1, 32, 64);
            if (q < 2) {
                s_p2n[img2][T * 4 + q * 2    ][oc] = (half_t)(0.25f * p0);
                s_p2n[img2][T * 4 + q * 2 + 1][oc] = (half_t)(0.25f * p1);
            }
        }
    }
    __syncthreads();

    // ---- stage 3 (MFMA, block-level): waves 0/1; tile = wave (oc base tile*16).
    // A[m=img*4+win][k=tap*16+ic] ; lane m=lane&15, chunk k = c*32 + quad*8 + j.
    if ((tid >> 6) < 2) {
        const int tile = tid >> 6;
        const int lane = tid & 63;
        const int n    = lane & 15;
        const int quad = lane >> 4;
        const int oc   = tile * 16 + n;
        const int am   = lane & 15;            // A row index held by this lane
        const int aimg = am >> 2;
        const int awin = am & 3;
        const int au   = awin >> 1, av = awin & 1;
        const int icb  = (quad & 1) * 8;

        float bias = b3g[oc];
        f32x4 acc;
        acc[0] = bias; acc[1] = bias; acc[2] = bias; acc[3] = bias;
        #pragma unroll
        for (int c = 0; c < 5; c++) {
            const int tap = c * 2 + (quad >> 1);
            f16x8 A;
            if (tap < 9) {
                const int i = tap / 3, j = tap - 3 * i;
                A = *(const f16x8*)&s_p2n[aimg][(au + i) * 4 + (av + j)][icb];
            } else {
                #pragma unroll
                for (int z = 0; z < 8; z++) A[z] = (half_t)0.f;
            }
            f16x8 B = *(const f16x8*)&w3B[((tile * 5 + c) * 64 + lane) * 8];
            acc = __builtin_amdgcn_mfma_f32_16x16x32_f16(A, B, acc, 0, 0, 0);
        }
        // D: row = quad*4 + reg -> img = quad, win = reg. relu + pool over the 4 windows.
        float s = fmaxf(acc[0], 0.f) + fmaxf(acc[1], 0.f) +
                  fmaxf(acc[2], 0.f) + fmaxf(acc[3], 0.f);
        s_p3[quad][oc] = 0.25f * s;
    }
    __syncthreads();

    // ---- dense + shfl softmax + guards (per wave = per image)
    {
        float logit = -1e30f;
        if (t6 < 10) {
            float acc = bdg[t6];
            #pragma unroll
            for (int c2 = 0; c2 < 32; c2++) acc += s_p3[img2][c2] * wdt[c2 * 10 + t6];
            logit = acc;
        }
        float mx = logit;
        #pragma unroll
        for (int s = 1; s < 16; s <<= 1) mx = fmaxf(mx, __shfl_xor(mx, s, 16));
        float e = (t6 < 10) ? __expf(logit - mx) : 0.f;
        float ssum = e;
        #pragma unroll
        for (int s = 1; s < 16; s <<= 1) ssum += __shfl_xor(ssum, s, 16);
        float p = e / ssum;                        // lanes 10..15 -> p = 0
        const int m = mbase + img2;
        if (t6 < 10) out[(size_t)m * 10 + t6] = p; // all_cnn_preds (N,B,10)

        // guards: [p8, p4+p6, p0+p2, p7+p9, p5, p1+p3]; 0xF slot reads lane 15 (p=0)
        const int sh = (t6 < 6 ? t6 : 0) * 4;
        const int ia = (0x157048 >> sh) & 0xF;
        const int ib = (0x3F926F >> sh) & 0xF;
        float pa = __shfl(p, ia, 16);
        float pb = __shfl(p, ib, 16);
        if (t6 < 6)
            out[81920 + (size_t)m * 6 + t6] = pa + pb;    // all_guard_preds (N,B,6)
    }
}

// 11 blocks x 256 threads. lane = bb*10 + j inside a wave (6 batches/wave).
__global__ __launch_bounds__(256) void sfa_kernel(
    const float* __restrict__ trans,
    const float* __restrict__ out_guards,   // = out (guards at +81920)
    float* __restrict__ out)
{
    __shared__ float M[600];           // [r][i][j]
    const int tid  = threadIdx.x;
    const int lane = tid & 63;
    const int wv   = tid >> 6;

    if (tid < 54) {
        int r = tid / 9, i = tid - r * 9;
        const float* row = trans + (size_t)(r * 9 + i) * 10;
        float x[10], mx = -1e30f;
        #pragma unroll
        for (int j = 0; j < 10; j++) { x[j] = 10.f * row[j]; mx = fmaxf(mx, x[j]); }
        float s = 0.f;
        #pragma unroll
        for (int j = 0; j < 10; j++) { x[j] = __expf(x[j] - mx); s += x[j]; }
        float inv = 1.f / s;
        #pragma unroll
        for (int j = 0; j < 10; j++) M[(r * 9 + i) * 10 + j] = x[j] * inv;
    }
    __syncthreads();

    const int bb    = lane / 10;
    const int j     = lane - bb * 10;
    const int base  = bb * 10;
    const bool ok   = (bb < 6);
    int batch = blockIdx.x * 24 + wv * 6 + bb;
    const bool live = ok && (batch < 256);
    if (!live) batch = 0;

    float Mreg[54];
    #pragma unroll
    for (int k = 0; k < 54; k++) Mreg[k] = M[k * 10 + j];

    float stj = (j == 0) ? 1.f : 0.f;
    const float* gbase = out_guards + 81920;

    for (int nn = 0; nn < 32; nn++) {
        const float* gp = gbase + ((size_t)nn * 256 + batch) * 6;
        float2 ga = *(const float2*)(gp);
        float2 gb = *(const float2*)(gp + 2);
        float2 gc = *(const float2*)(gp + 4);
        float g[6] = {ga.x, ga.y, gb.x, gb.y, gc.x, gc.y};

        float st[10];
        #pragma unroll
        for (int i = 0; i < 10; i++) st[i] = __shfl(stj, base + i, 64);

        float gsum = g[0] + g[1] + g[2] + g[3] + g[4] + g[5];
        float ns = (j == 9) ? gsum * st[9] : 0.f;   // accepting row
        #pragma unroll
        for (int r = 0; r < 6; r++) {
            float h = 0.f;
            #pragma unroll
            for (int i = 0; i < 9; i++) h += st[i] * Mreg[r * 9 + i];
            ns += g[r] * h;
        }
        stj = ns;
    }
    if (live) out[131072 + (size_t)batch * 10 + j] = stj;   // state_final (B,10)
}

extern "C" void kernel_launch(void* const* d_in, const int* in_sizes, int n_in,
                              void* d_out, int out_size, void* d_ws, size_t ws_size,
                              hipStream_t stream) {
    const float* seq = (const float*)d_in[0];
    const float* w1  = (const float*)d_in[1];
    const float* b1  = (const float*)d_in[2];
    const float* w2  = (const float*)d_in[3];
    const float* b2  = (const float*)d_in[4];
    const float* w3  = (const float*)d_in[5];
    const float* b3  = (const float*)d_in[6];
    const float* wd  = (const float*)d_in[7];
    const float* bd  = (const float*)d_in[8];
    const float* tr  = (const float*)d_in[9];
    float* out = (float*)d_out;
    float* wsW = (float*)d_ws;             // wdt + w2B + w3B fragments

    prep_kernel<<<1, 256, 0, stream>>>(w2, w3, wd, wsW);
    cnn_kernel<<<2048, 256, 0, stream>>>(seq, w1, b1, b2, b3, bd, wsW, out);
    sfa_kernel<<<11, 256, 0, stream>>>(tr, out, out);
}